// Round 4
// baseline (1022.517 us; speedup 1.0000x reference)
//
#include <hip/hip_runtime.h>

typedef short bf16x8_t __attribute__((ext_vector_type(8)));
typedef short bf16x4_t __attribute__((ext_vector_type(4)));
typedef float f32x4_t  __attribute__((ext_vector_type(4)));

#define N_TOT 16384
#define KNB   32
#define DDIM  256
#define DCAT  512

static __device__ __forceinline__ unsigned short f2bf(float f) {
  union { float fv; unsigned int u; } v; v.fv = f;
  const unsigned int u = v.u;
  return (unsigned short)((u + 0x7fffu + ((u >> 16) & 1u)) >> 16);  // RNE
}

// ---------------------------------------------------------------------------
// Fused neighbor attention: per n, compute K/V-proj via bf16 MFMA with Wk/Wv
// resident in registers, energies + masked softmax + context in-register.
// Writes context [N,256] f32. Q (with bq) precomputed by gemm_kernel<0>.
// ---------------------------------------------------------------------------
__global__ __launch_bounds__(512, 2) void attn_kernel(
    const float* __restrict__ nb,
    const float* __restrict__ Wk, const float* __restrict__ bk,
    const float* __restrict__ Wv, const float* __restrict__ bv,
    const float* __restrict__ Q,
    float* __restrict__ context)
{
  __shared__ unsigned char xs[KNB * 512];   // bf16 [32][256], XOR-swizzled rows
  __shared__ float e_lds[8][KNB];
  __shared__ float att_lds[KNB];
  __shared__ float rowsum[KNB];

  const int tid  = threadIdx.x;
  const int lane = tid & 63;
  const int w    = tid >> 6;    // wave 0..7
  const int l15  = lane & 15;
  const int lq   = lane >> 4;   // 0..3
  const int wc   = w * 32;      // this wave's output-dim base

  // --- persistent weight fragments: wave covers cols [wc, wc+32) ---
  bf16x8_t wkf[2][8], wvf[2][8];
  float bkv[2], bvv[2];
  #pragma unroll
  for (int ct = 0; ct < 2; ++ct) {
    const int o = wc + ct * 16 + l15;
    bkv[ct] = bk[o];
    bvv[ct] = bv[o];
    #pragma unroll
    for (int ks = 0; ks < 8; ++ks) {
      const int kc = ks * 32 + lq * 8;   // frag k = 8*(lane>>4)+e within 32-block
      const float4 a0 = *(const float4*)(Wk + o * DDIM + kc);
      const float4 a1 = *(const float4*)(Wk + o * DDIM + kc + 4);
      const float4 b0 = *(const float4*)(Wv + o * DDIM + kc);
      const float4 b1 = *(const float4*)(Wv + o * DDIM + kc + 4);
      bf16x8_t fk, fv;
      fk[0]=(short)f2bf(a0.x); fk[1]=(short)f2bf(a0.y); fk[2]=(short)f2bf(a0.z); fk[3]=(short)f2bf(a0.w);
      fk[4]=(short)f2bf(a1.x); fk[5]=(short)f2bf(a1.y); fk[6]=(short)f2bf(a1.z); fk[7]=(short)f2bf(a1.w);
      fv[0]=(short)f2bf(b0.x); fv[1]=(short)f2bf(b0.y); fv[2]=(short)f2bf(b0.z); fv[3]=(short)f2bf(b0.w);
      fv[4]=(short)f2bf(b1.x); fv[5]=(short)f2bf(b1.y); fv[6]=(short)f2bf(b1.z); fv[7]=(short)f2bf(b1.w);
      wkf[ct][ks] = fk; wvf[ct][ks] = fv;
    }
  }

  const int row_s = tid >> 4;          // staging row 0..31 (t/16)
  const int cb    = (tid & 15) * 32;   // byte col base (16 floats -> 32 B bf16)
  const int sw_s  = (row_s & 15) << 4; // write-side swizzle

  int n = blockIdx.x;
  float4 xr0, xr1, xr2, xr3;
  {
    const float4* src = (const float4*)(nb + (size_t)n * (KNB * DDIM) + row_s * DDIM + (tid & 15) * 16);
    xr0 = src[0]; xr1 = src[1]; xr2 = src[2]; xr3 = src[3];
  }

  while (n < N_TOT) {
    // ---- phase 1: convert+write LDS, rowsum (mask), q frags, prefetch next ----
    bf16x8_t p0, p1;
    p0[0]=(short)f2bf(xr0.x); p0[1]=(short)f2bf(xr0.y); p0[2]=(short)f2bf(xr0.z); p0[3]=(short)f2bf(xr0.w);
    p0[4]=(short)f2bf(xr1.x); p0[5]=(short)f2bf(xr1.y); p0[6]=(short)f2bf(xr1.z); p0[7]=(short)f2bf(xr1.w);
    p1[0]=(short)f2bf(xr2.x); p1[1]=(short)f2bf(xr2.y); p1[2]=(short)f2bf(xr2.z); p1[3]=(short)f2bf(xr2.w);
    p1[4]=(short)f2bf(xr3.x); p1[5]=(short)f2bf(xr3.y); p1[6]=(short)f2bf(xr3.z); p1[7]=(short)f2bf(xr3.w);
    float rs = xr0.x+xr0.y+xr0.z+xr0.w + xr1.x+xr1.y+xr1.z+xr1.w
             + xr2.x+xr2.y+xr2.z+xr2.w + xr3.x+xr3.y+xr3.z+xr3.w;
    unsigned char* base = xs + row_s * 512;
    *(bf16x8_t*)(base + ((cb +  0) ^ sw_s)) = p0;
    *(bf16x8_t*)(base + ((cb + 16) ^ sw_s)) = p1;
    #pragma unroll
    for (int d = 1; d < 16; d <<= 1) rs += __shfl_xor(rs, d);
    if (l15 == 0) rowsum[row_s] = rs;

    const float qf0 = Q[(size_t)n * DDIM + wc + l15];
    const float qf1 = Q[(size_t)n * DDIM + wc + 16 + l15];

    const int n_next = n + gridDim.x;
    if (n_next < N_TOT) {   // T14: issue next-n loads; they fly under the MFMAs
      const float4* src = (const float4*)(nb + (size_t)n_next * (KNB * DDIM) + row_s * DDIM + (tid & 15) * 16);
      xr0 = src[0]; xr1 = src[1]; xr2 = src[2]; xr3 = src[3];
    }

    __syncthreads();

    // ---- phase 2: K/V projection MFMAs (f32 accum) ----
    const f32x4_t z4 = {0.f, 0.f, 0.f, 0.f};
    f32x4_t accK[2][2], accV[2][2];
    accK[0][0]=z4; accK[0][1]=z4; accK[1][0]=z4; accK[1][1]=z4;
    accV[0][0]=z4; accV[0][1]=z4; accV[1][0]=z4; accV[1][1]=z4;
    #pragma unroll
    for (int ks = 0; ks < 8; ++ks) {
      bf16x8_t af[2];
      #pragma unroll
      for (int rt = 0; rt < 2; ++rt) {
        const int row = rt * 16 + l15;
        const int off = (ks * 64 + lq * 16) ^ ((row & 15) << 4);
        af[rt] = *(const bf16x8_t*)(xs + row * 512 + off);
      }
      #pragma unroll
      for (int ct = 0; ct < 2; ++ct) {
        #pragma unroll
        for (int rt = 0; rt < 2; ++rt) {
          accK[ct][rt] = __builtin_amdgcn_mfma_f32_16x16x32_bf16(af[rt], wkf[ct][ks], accK[ct][rt], 0, 0, 0);
          accV[ct][rt] = __builtin_amdgcn_mfma_f32_16x16x32_bf16(af[rt], wvf[ct][ks], accV[ct][rt], 0, 0, 0);
        }
      }
    }

    // ---- phase 3: energies e[r] = sum_o (K[r,o]+bk[o]) * q[o] ----
    float ep[8];
    #pragma unroll
    for (int rt = 0; rt < 2; ++rt)
      #pragma unroll
      for (int j = 0; j < 4; ++j)
        ep[rt*4+j] = (accK[0][rt][j] + bkv[0]) * qf0 + (accK[1][rt][j] + bkv[1]) * qf1;
    #pragma unroll
    for (int d = 1; d < 16; d <<= 1) {
      #pragma unroll
      for (int i = 0; i < 8; ++i) ep[i] += __shfl_xor(ep[i], d);
    }
    if (l15 == 0) {
      #pragma unroll
      for (int rt = 0; rt < 2; ++rt)
        #pragma unroll
        for (int j = 0; j < 4; ++j)
          e_lds[w][rt * 16 + lq * 4 + j] = ep[rt*4+j];
    }
    __syncthreads();

    // ---- phase 4: masked softmax over 32 neighbors (wave 0) ----
    if (tid < KNB) {
      float e = 0.f;
      #pragma unroll
      for (int ww = 0; ww < 8; ++ww) e += e_lds[ww][tid];
      if (rowsum[tid] == 0.0f) e = 1e-12f;       // faithful: fill, not -inf
      float m = e;
      #pragma unroll
      for (int d = 1; d < 32; d <<= 1) m = fmaxf(m, __shfl_xor(m, d));
      const float p = expf(e - m);
      float s = p;
      #pragma unroll
      for (int d = 1; d < 32; d <<= 1) s += __shfl_xor(s, d);
      att_lds[tid] = p / s;
    }
    __syncthreads();

    // ---- phase 5: context[o] = sum_r att[r]*V[r,o] + bv[o]  (sum att == 1) ----
    float c0 = 0.f, c1 = 0.f;
    #pragma unroll
    for (int rt = 0; rt < 2; ++rt)
      #pragma unroll
      for (int j = 0; j < 4; ++j) {
        const float a = att_lds[rt * 16 + lq * 4 + j];
        c0 += a * accV[0][rt][j];
        c1 += a * accV[1][rt][j];
      }
    c0 += __shfl_xor(c0, 16); c0 += __shfl_xor(c0, 32);
    c1 += __shfl_xor(c1, 16); c1 += __shfl_xor(c1, 32);
    if (lane < 16) {
      context[(size_t)n * DDIM + wc + l15]      = c0 + bvv[0];
      context[(size_t)n * DDIM + wc + 16 + l15] = c1 + bvv[1];
    }

    n = n_next;
  }
}

// ---------------------------------------------------------------------------
// Generic 128x128-tile bf16-MFMA GEMM, A[M,K] f32, B[Ncols,K] f32 (weights
// [out,in]); converts to bf16 during LDS staging. MODE 0: C = A*B^T + bias.
// MODE 1 (gate+BN finalize): out = relu(A*B^T+bias) * relu(BN(bnin)).
// ---------------------------------------------------------------------------
template <int MODE>
__global__ __launch_bounds__(256, 2) void gemm_kernel(
    const float* __restrict__ A, const float* __restrict__ B,
    const float* __restrict__ bias, float* __restrict__ C,
    int Kdim, int ldo,
    const float* __restrict__ bnin, const float* __restrict__ stats,
    const float* __restrict__ gamma, const float* __restrict__ beta)
{
  __shared__ short As[128 * 32];
  __shared__ short Bs[128 * 32];

  const int tid  = threadIdx.x;
  const int lane = tid & 63;
  const int w    = tid >> 6;
  const int l15  = lane & 15;
  const int lq   = lane >> 4;
  const int wr   = (w >> 1) * 64;
  const int wn   = (w & 1) * 64;
  const int m0 = blockIdx.x * 128;
  const int n0 = blockIdx.y * 128;

  const f32x4_t z4 = {0.f,0.f,0.f,0.f};
  f32x4_t acc[4][4];
  #pragma unroll
  for (int i = 0; i < 4; ++i)
    #pragma unroll
    for (int j = 0; j < 4; ++j) acc[i][j] = z4;

  const int sr = tid >> 3;        // 0..31
  const int sc = (tid & 7) * 4;   // 0..28

  for (int kt = 0; kt < Kdim; kt += 32) {
    #pragma unroll
    for (int i = 0; i < 4; ++i) {
      const int row = sr + i * 32;
      const float4 va = *(const float4*)(A + (size_t)(m0 + row) * Kdim + kt + sc);
      const float4 vb = *(const float4*)(B + (size_t)(n0 + row) * Kdim + kt + sc);
      bf16x4_t pa, pb;
      pa[0]=(short)f2bf(va.x); pa[1]=(short)f2bf(va.y); pa[2]=(short)f2bf(va.z); pa[3]=(short)f2bf(va.w);
      pb[0]=(short)f2bf(vb.x); pb[1]=(short)f2bf(vb.y); pb[2]=(short)f2bf(vb.z); pb[3]=(short)f2bf(vb.w);
      *(bf16x4_t*)(&As[row * 32 + sc]) = pa;
      *(bf16x4_t*)(&Bs[row * 32 + sc]) = pb;
    }
    __syncthreads();
    bf16x8_t af[4], bfr[4];
    #pragma unroll
    for (int i = 0; i < 4; ++i) {
      af[i]  = *(const bf16x8_t*)(&As[(wr + i * 16 + l15) * 32 + lq * 8]);
      bfr[i] = *(const bf16x8_t*)(&Bs[(wn + i * 16 + l15) * 32 + lq * 8]);
    }
    #pragma unroll
    for (int i = 0; i < 4; ++i)
      #pragma unroll
      for (int j = 0; j < 4; ++j)
        acc[i][j] = __builtin_amdgcn_mfma_f32_16x16x32_bf16(af[i], bfr[j], acc[i][j], 0, 0, 0);
    __syncthreads();
  }

  #pragma unroll
  for (int j = 0; j < 4; ++j) {
    const int col = n0 + wn + j * 16 + l15;
    const float bs = bias[col];
    float mean = 0.f, rstd = 0.f, gm = 0.f, bt = 0.f;
    if constexpr (MODE == 1) {
      mean = stats[col] * (1.f / 16384.f);
      const float var = stats[DCAT + col] * (1.f / 16384.f) - mean * mean;
      rstd = 1.f / sqrtf(var + 1e-5f);
      gm = gamma[col]; bt = beta[col];
    }
    #pragma unroll
    for (int i = 0; i < 4; ++i) {
      #pragma unroll
      for (int jj = 0; jj < 4; ++jj) {
        const int row = m0 + wr + i * 16 + lq * 4 + jj;
        const float v = acc[i][j][jj] + bs;
        if constexpr (MODE == 0) {
          C[(size_t)row * ldo + col] = v;
        } else {
          const float g = fmaxf(v, 0.f);
          const float o = bnin[(size_t)row * DCAT + col];
          const float bn = gm * (o - mean) * rstd + bt;
          C[(size_t)row * ldo + col] = g * fmaxf(bn, 0.f);
        }
      }
    }
  }
}

// ---------------------------------------------------------------------------
// BN batch statistics: column sums / sums-of-squares of outbuf [N,512].
// ---------------------------------------------------------------------------
__global__ void stats_kernel(const float* __restrict__ outb, float* __restrict__ stats) {
  const int c = threadIdx.x;   // 512 threads = one column each
  float s = 0.f, s2 = 0.f;
  for (int r = blockIdx.x; r < N_TOT; r += gridDim.x) {
    const float v = outb[(size_t)r * DCAT + c];
    s += v; s2 += v * v;
  }
  atomicAdd(&stats[c], s);
  atomicAdd(&stats[DCAT + c], s2);
}

extern "C" void kernel_launch(void* const* d_in, const int* in_sizes, int n_in,
                              void* d_out, int out_size, void* d_ws, size_t ws_size,
                              hipStream_t stream) {
  (void)in_sizes; (void)n_in; (void)out_size; (void)ws_size;
  const float* input = (const float*)d_in[0];
  const float* nbi   = (const float*)d_in[1];
  const float* Wq  = (const float*)d_in[2];
  const float* bq  = (const float*)d_in[3];
  const float* Wk  = (const float*)d_in[4];
  const float* bk  = (const float*)d_in[5];
  const float* Wv  = (const float*)d_in[6];
  const float* bv  = (const float*)d_in[7];
  const float* Wno = (const float*)d_in[8];
  const float* bno = (const float*)d_in[9];
  const float* Wio = (const float*)d_in[10];
  const float* bio = (const float*)d_in[11];
  const float* Wg  = (const float*)d_in[12];
  const float* bg  = (const float*)d_in[13];
  const float* gamma = (const float*)d_in[14];
  const float* beta  = (const float*)d_in[15];

  float* Q       = (float*)d_ws;                      // N*256
  float* contextb = Q + (size_t)N_TOT * DDIM;         // N*256
  float* outbuf  = contextb + (size_t)N_TOT * DDIM;   // N*512 (concat output)
  float* stats   = outbuf + (size_t)N_TOT * DCAT;     // 1024

  hipMemsetAsync(stats, 0, 2 * DCAT * sizeof(float), stream);

  // Q = input@Wq^T + bq
  gemm_kernel<0><<<dim3(128, 2), dim3(256), 0, stream>>>(
      input, Wq, bq, Q, DDIM, DDIM, nullptr, nullptr, nullptr, nullptr);
  // self_out -> outbuf[:, 0:256]
  gemm_kernel<0><<<dim3(128, 2), dim3(256), 0, stream>>>(
      input, Wio, bio, outbuf, DDIM, DCAT, nullptr, nullptr, nullptr, nullptr);
  // fused neighbor attention -> context
  attn_kernel<<<dim3(256), dim3(512), 0, stream>>>(nbi, Wk, bk, Wv, bv, Q, contextb);
  // neigh_out -> outbuf[:, 256:512]
  gemm_kernel<0><<<dim3(128, 2), dim3(256), 0, stream>>>(
      contextb, Wno, bno, outbuf + 256, DDIM, DCAT, nullptr, nullptr, nullptr, nullptr);
  // BN batch stats
  stats_kernel<<<dim3(128), dim3(512), 0, stream>>>(outbuf, stats);
  // gate GEMM + fused BN/relu finalize -> d_out
  gemm_kernel<1><<<dim3(128, 4), dim3(256), 0, stream>>>(
      outbuf, Wg, bg, (float*)d_out, DCAT, DCAT, outbuf, stats, gamma, beta);
}